// Round 1
// baseline (263.539 us; speedup 1.0000x reference)
//
#include <hip/hip_runtime.h>

typedef short short8 __attribute__((ext_vector_type(8)));
typedef float f32x4 __attribute__((ext_vector_type(4)));
typedef float f32x16 __attribute__((ext_vector_type(16)));
typedef unsigned short u16x4 __attribute__((ext_vector_type(4)));

constexpr int NB = 16, CIN = 128, LIN = 2048, CO = 256;
constexpr int SL = 2041;                 // output sequence length
constexpr int MT = NB * SL;              // 32656 valid rows
constexpr int MP = 32768;                // padded rows
constexpr int XTS = 136;                 // xT row stride (elems): 16B-aligned

// ---- workspace layout (bytes, all 256-aligned) ----
constexpr size_t XT_OFF = 0;
constexpr size_t XT_SZ  = (size_t)NB*LIN*XTS*2 + 65536;  // bf16 xT [n][s][136] + OOB slack
constexpr size_t CW_OFF = XT_OFF + XT_SZ;
constexpr size_t CW_SZ  = (size_t)CO*CIN*8*2;            // conv_w bf16 [256][1024], kk=kp*128+ci
constexpr size_t WQ_OFF = CW_OFF + CW_SZ;
constexpr size_t WB_SZ  = (size_t)CO*CO*2;
constexpr size_t WK_OFF = WQ_OFF + WB_SZ;
constexpr size_t WV_OFF = WK_OFF + WB_SZ;
constexpr size_t H_OFF  = WV_OFF + WB_SZ;
constexpr size_t HB_SZ  = (size_t)MP*CO*2;               // 16 MB each
constexpr size_t Q_OFF  = H_OFF + HB_SZ;
constexpr size_t K_OFF  = Q_OFF + HB_SZ;
constexpr size_t VT_OFF = K_OFF + HB_SZ;                 // v transposed [256][16][2048]

__device__ inline unsigned short f2bf(float f) {
  union { float f; unsigned int u; } v; v.f = f;
  unsigned int r = v.u + 0x7fffu + ((v.u >> 16) & 1u);
  return (unsigned short)(r >> 16);
}

// CK-style LDS barrier: waits only lgkmcnt(0) (ds ops), does NOT drain vmcnt.
__device__ inline void sync_lds() {
  __asm__ volatile("" ::: "memory");
  __builtin_amdgcn_s_waitcnt(0xc07f);   // lgkmcnt(0)
  __builtin_amdgcn_s_barrier();
  __asm__ volatile("" ::: "memory");
}
__device__ inline void barrier_only() {
  __asm__ volatile("" ::: "memory");
  __builtin_amdgcn_s_barrier();
  __asm__ volatile("" ::: "memory");
}

#if defined(__has_builtin)
#if __has_builtin(__builtin_amdgcn_global_load_lds)
#define HAVE_GLDS 1
#endif
#endif

__device__ inline void gld16(const unsigned short* g, void* l) {
#ifdef HAVE_GLDS
  __builtin_amdgcn_global_load_lds(
      (const __attribute__((address_space(1))) void*)g,
      (__attribute__((address_space(3))) void*)l, 16, 0, 0);
#else
  *(short8*)l = *(const short8*)g;
#endif
}

// pack two f32 -> one u32 of 2 bf16 (low = a, high = b); no builtin on gfx950
__device__ inline unsigned int cvt_pk_bf16(float a, float b) {
  unsigned int r;
  asm("v_cvt_pk_bf16_f32 %0, %1, %2" : "=v"(r) : "v"(a), "v"(b));
  return r;
}
// vdst lanes[32:63] <-> vsrc lanes[0:31]; both results used (m214 T12 recipe)
__device__ inline void swap32(unsigned int& a, unsigned int& b) {
  asm("v_permlane32_swap_b32 %0, %1" : "+v"(a), "+v"(b));
}

// ---------------- x transpose + bf16: [16][128][2048] f32 -> [16][2048][136] bf16 ----------------
__global__ void xpose_kernel(const float* __restrict__ x, unsigned short* __restrict__ xt) {
  __shared__ float tile[32][33];
  const int tx = threadIdx.x, ty = threadIdx.y;
  const int s0 = blockIdx.x * 32, c0 = blockIdx.y * 32, n = blockIdx.z;
  #pragma unroll
  for (int r = 0; r < 4; ++r)
    tile[ty * 4 + r][tx] = x[((size_t)(n * CIN + c0 + ty * 4 + r)) * LIN + s0 + tx];
  __syncthreads();
  #pragma unroll
  for (int r = 0; r < 4; ++r)
    xt[((size_t)(n * LIN + s0 + ty * 4 + r)) * XTS + c0 + tx] = f2bf(tile[tx][ty * 4 + r]);
}

// ---------------- conv weight reorder ----------------
__global__ void wconv_kernel(const float* __restrict__ w, unsigned short* __restrict__ o) {
  int idx = blockIdx.x * 256 + threadIdx.x;
  int co = idx >> 10, r = idx & 1023, kp = r >> 7, ci = r & 127;
  o[idx] = f2bf(w[co * 1024 + ci * 8 + kp]);
}

// ---------------- q/k/v weight cvt ----------------
__global__ void wqkv_kernel(const float* __restrict__ a, const float* __restrict__ b,
                            const float* __restrict__ c, unsigned short* __restrict__ oa,
                            unsigned short* __restrict__ ob, unsigned short* __restrict__ oc) {
  int z = blockIdx.x >> 6, lb = blockIdx.x & 63;
  const float* src = (z == 0) ? a : (z == 1) ? b : c;
  unsigned short* dst = (z == 0) ? oa : (z == 1) ? ob : oc;
  int i = (lb * 256 + threadIdx.x) * 4;
  float4 v = *(const float4*)(src + i);
  u16x4 r;
  r.x = f2bf(v.x); r.y = f2bf(v.y); r.z = f2bf(v.z); r.w = f2bf(v.w);
  *(u16x4*)(dst + i) = r;
}

// ---------------- conv as implicit GEMM: reg-prefetch dbuf weights ----------------
__global__ __launch_bounds__(256) void conv_gemm(
    const unsigned short* __restrict__ xt,   // [16][2048][136] bf16
    const unsigned short* __restrict__ wb,   // [256][1024] bf16 (kk = kp*128+ci)
    const float* __restrict__ bias,
    unsigned short* __restrict__ h)          // [MP][256] bf16
{
  __shared__ unsigned short sX[18432];       // 36 KB x-window
  __shared__ unsigned short sB[2][4096];     // 2 x 8 KB weight chunk, chunk-swizzled
  const int tid = threadIdx.x;
  const int w = tid >> 6, lane = tid & 63, quad = lane >> 4, l16 = lane & 15;
  const int n  = blockIdx.y;
  const int s0 = blockIdx.x * 128;
  const int d0 = blockIdx.z * 128;

  {
    const unsigned short* xbase = xt + ((size_t)n * LIN + s0) * XTS;
    #pragma unroll
    for (int i = 0; i < 9; ++i) {
      int u = i * 256 + tid;
      gld16(xbase + u * 8, ((char*)sX) + u * 16);
    }
  }

  const int brow0 = tid >> 2, bkgs = tid & 3;
  short8 breg[2];
  #pragma unroll
  for (int i2 = 0; i2 < 2; ++i2) {
    int row = i2 * 64 + brow0;
    int kg = bkgs ^ ((row >> 1) & 3);
    breg[i2] = *(const short8*)(wb + (size_t)(d0 + row) * 1024 + kg * 8);
  }
  #pragma unroll
  for (int i2 = 0; i2 < 2; ++i2)
    *(short8*)(&sB[0][(i2 * 256 + tid) * 8]) = breg[i2];
  __syncthreads();                          // full drain once (X DMA + sB[0])

  f32x4 acc[2][8];
  #pragma unroll
  for (int i = 0; i < 2; ++i)
    #pragma unroll
    for (int j = 0; j < 8; ++j) acc[i][j] = (f32x4){0.f, 0.f, 0.f, 0.f};

  for (int kc = 0; kc < 32; ++kc) {
    const int kcn = (kc < 31) ? kc + 1 : kc;
    const int kpn = kcn >> 2, ci0n = (kcn & 3) * 32;
    #pragma unroll
    for (int i2 = 0; i2 < 2; ++i2) {
      int row = i2 * 64 + brow0;
      int kg = bkgs ^ ((row >> 1) & 3);
      breg[i2] = *(const short8*)(wb + (size_t)(d0 + row) * 1024 + kpn * 128 + ci0n + kg * 8);
    }

    const int kp = kc >> 2, ci0 = (kc & 3) * 32;
    const unsigned short* sBc = sB[kc & 1];
    short8 bfr[8];
    #pragma unroll
    for (int j = 0; j < 8; ++j) {
      int r = j * 16 + l16;
      bfr[j] = *(const short8*)(sBc + r * 32 + (quad ^ ((r >> 1) & 3)) * 8);
    }
    #pragma unroll
    for (int i = 0; i < 2; ++i) {
      int srow = w * 32 + i * 16 + l16;
      short8 afr = *(const short8*)(sX + (srow + kp) * XTS + ci0 + quad * 8);
      #pragma unroll
      for (int j = 0; j < 8; ++j)
        acc[i][j] = __builtin_amdgcn_mfma_f32_16x16x32_bf16(afr, bfr[j], acc[i][j], 0, 0, 0);
    }

    #pragma unroll
    for (int i2 = 0; i2 < 2; ++i2)
      *(short8*)(&sB[(kc + 1) & 1][(i2 * 256 + tid) * 8]) = breg[i2];
    sync_lds();
  }

  #pragma unroll
  for (int i = 0; i < 2; ++i)
    #pragma unroll
    for (int j = 0; j < 8; ++j) {
      int col = d0 + j * 16 + l16;
      float bv = bias[col];
      #pragma unroll
      for (int jj = 0; jj < 4; ++jj) {
        int s = s0 + w * 32 + i * 16 + quad * 4 + jj;
        if (s < SL) {
          float val = fmaxf(acc[i][j][jj] + bv, 0.f);
          h[(size_t)(n * SL + s) * CO + col] = f2bf(val);
        }
      }
    }
}

// ---------------- q/k/v linear GEMMs: reg-prefetch dbuf A and B ----------------
__global__ __launch_bounds__(256) void lin_gemm(
    const unsigned short* __restrict__ A,    // h [MP][256]
    const unsigned short* __restrict__ Bq, const unsigned short* __restrict__ Bk,
    const unsigned short* __restrict__ Bv,
    const float* __restrict__ biq, const float* __restrict__ bik,
    const float* __restrict__ biv,
    unsigned short* __restrict__ qb, unsigned short* __restrict__ kb,
    unsigned short* __restrict__ vtb)
{
  __shared__ unsigned short sA[2][4096];
  __shared__ unsigned short sB[2][4096];
  const int tid = threadIdx.x;
  const int w = tid >> 6, lane = tid & 63, quad = lane >> 4, l16 = lane & 15;
  const int m0 = blockIdx.x * 128, d0 = blockIdx.y * 128, z = blockIdx.z;
  const unsigned short* B = (z == 0) ? Bq : (z == 1) ? Bk : Bv;
  const float* bias        = (z == 0) ? biq : (z == 1) ? bik : biv;

  const int brow0 = tid >> 2, bkgs = tid & 3;
  short8 areg[2], breg[2];
  #pragma unroll
  for (int i2 = 0; i2 < 2; ++i2) {
    int row = i2 * 64 + brow0;
    int kg = bkgs ^ ((row >> 1) & 3);
    areg[i2] = *(const short8*)(A + (size_t)(m0 + row) * CO + kg * 8);
    breg[i2] = *(const short8*)(B + (size_t)(d0 + row) * CO + kg * 8);
  }
  #pragma unroll
  for (int i2 = 0; i2 < 2; ++i2) {
    *(short8*)(&sA[0][(i2 * 256 + tid) * 8]) = areg[i2];
    *(short8*)(&sB[0][(i2 * 256 + tid) * 8]) = breg[i2];
  }
  sync_lds();

  f32x4 acc[2][8];
  #pragma unroll
  for (int i = 0; i < 2; ++i)
    #pragma unroll
    for (int j = 0; j < 8; ++j) acc[i][j] = (f32x4){0.f, 0.f, 0.f, 0.f};

  for (int kc = 0; kc < 8; ++kc) {
    const int kcn = (kc < 7) ? kc + 1 : kc;
    #pragma unroll
    for (int i2 = 0; i2 < 2; ++i2) {
      int row = i2 * 64 + brow0;
      int kg = bkgs ^ ((row >> 1) & 3);
      areg[i2] = *(const short8*)(A + (size_t)(m0 + row) * CO + kcn * 32 + kg * 8);
      breg[i2] = *(const short8*)(B + (size_t)(d0 + row) * CO + kcn * 32 + kg * 8);
    }

    const unsigned short* sAc = sA[kc & 1];
    const unsigned short* sBc = sB[kc & 1];
    short8 afr[2], bfr[8];
    #pragma unroll
    for (int i = 0; i < 2; ++i) {
      int r = w * 32 + i * 16 + l16;
      afr[i] = *(const short8*)(sAc + r * 32 + (quad ^ ((r >> 1) & 3)) * 8);
    }
    #pragma unroll
    for (int j = 0; j < 8; ++j) {
      int r = j * 16 + l16;
      bfr[j] = *(const short8*)(sBc + r * 32 + (quad ^ ((r >> 1) & 3)) * 8);
    }
    #pragma unroll
    for (int i = 0; i < 2; ++i)
      #pragma unroll
      for (int j = 0; j < 8; ++j)
        acc[i][j] = __builtin_amdgcn_mfma_f32_16x16x32_bf16(afr[i], bfr[j], acc[i][j], 0, 0, 0);

    #pragma unroll
    for (int i2 = 0; i2 < 2; ++i2) {
      *(short8*)(&sA[(kc + 1) & 1][(i2 * 256 + tid) * 8]) = areg[i2];
      *(short8*)(&sB[(kc + 1) & 1][(i2 * 256 + tid) * 8]) = breg[i2];
    }
    sync_lds();
  }

  #pragma unroll
  for (int i = 0; i < 2; ++i)
    #pragma unroll
    for (int j = 0; j < 8; ++j) {
      int col = d0 + j * 16 + l16;
      float bv = bias[col];
      #pragma unroll
      for (int jj = 0; jj < 4; ++jj) {
        int m = m0 + w * 32 + i * 16 + quad * 4 + jj;
        float val = acc[i][j][jj] + bv;
        if (z == 0) {
          // fold the attention 1/sqrt(C)=1/16 score scale into q (exact pow2 in bf16)
          qb[(size_t)m * CO + col] = f2bf(val * 0.0625f);
        } else if (z == 1) {
          kb[(size_t)m * CO + col] = f2bf(val);
        } else if (m < MT) {
          int nn = m / SL, ss = m - nn * SL;
          vtb[(size_t)col * MP + nn * 2048 + ss] = f2bf(val);
        }
      }
    }
}

// ---------------- fused sigmoid attention: in-register P (T12), 1 barrier/iter ---------------
// grid 256, 512 threads = 8 waves (sr=w&3 s-range, tr=w>>2 t-half), s-tile 128, t-tile 64.
// LDS (128 KB): sK[2]: [64 t][32 slots x 16B] XOR-slot; sV[2]: [256 d][8 slots x 16B] XOR-slot.
// P never touches LDS: QK C-frag (col=s, row=(r&3)+8(r>>2)+4h) -> v_cvt_pk_bf16_f32 pairs ->
// v_permlane32_swap_b32 x2 per 16-chunk -> PV B-operand frags. Each wave owns its t-half of P,
// so PV accumulates a FULL-d (256) partial o[8]; tr-partners sum via LDS scratch at epilogue.
// Per iter: barrier -> STAGE next tile -> QK -> sigmoid+repack -> PV -> vmcnt(0)+lgkm+barrier.
__global__ __launch_bounds__(512, 2) void attn_kernel(
    const unsigned short* __restrict__ qb,   // [MP][256] (pre-scaled by 1/16)
    const unsigned short* __restrict__ kb,   // [MP][256]
    const unsigned short* __restrict__ vtb,  // [256][16][2048]
    float* __restrict__ out)                 // [16][256][2041]
{
  __shared__ unsigned short sK[2][16384];    // 2 x 32 KB
  __shared__ unsigned short sV[2][16384];    // 2 x 32 KB
  const int tid = threadIdx.x;
  const int w = tid >> 6, lane = tid & 63;
  const int half = lane >> 5, l32 = lane & 31;
  const int bidx = blockIdx.x;
  const int n = (bidx & 7) + ((bidx >> 7) << 3);   // XCD-pinned: 2 n's per XCD
  const int s0 = ((bidx >> 3) & 15) * 128;
  const int sr = w & 3, tr = w >> 2;         // tr = t-half owned in QK/P

  const unsigned short* kbN = kb + (size_t)(n * SL) * CO;
  const unsigned short* vbN = vtb + (size_t)n * 2048;

  // K: u = i*512+tid -> t = u>>5, slot = u&31; cell holds global chunk slot^(t&31).
  // V: u -> d = u>>3, slot = u&7; cell holds global t-chunk slot^(d&7).
#define STAGE_TILE(buf, tk)                                                      \
  {                                                                              \
    _Pragma("unroll")                                                            \
    for (int i = 0; i < 4; ++i) {                                                \
      int u = i * 512 + tid;                                                     \
      int t = u >> 5, sl = u & 31;                                               \
      gld16(kbN + (size_t)((tk) + t) * CO + ((sl ^ (t & 31)) << 3),              \
            ((char*)sK[buf]) + u * 16);                                          \
    }                                                                            \
    _Pragma("unroll")                                                            \
    for (int i = 0; i < 4; ++i) {                                                \
      int u = i * 512 + tid;                                                     \
      int d = u >> 3, sl = u & 7;                                                \
      gld16(vbN + (size_t)d * MP + (tk) + ((sl ^ (d & 7)) << 3),                 \
            ((char*)sV[buf]) + u * 16);                                          \
    }                                                                            \
  }

  STAGE_TILE(0, 0)

  // Q frags (B-operand): element (s = s0+sr*32+l32, c = kk*16+half*8+j)
  short8 qf[16];
  {
    const unsigned short* qp = qb + (size_t)(n * SL + s0 + sr * 32 + l32) * CO + half * 8;
    #pragma unroll
    for (int kk = 0; kk < 16; ++kk) qf[kk] = *(const short8*)(qp + kk * 16);
  }

  __builtin_amdgcn_s_waitcnt(0x0F70);        // vmcnt(0): tile0 + Q resident
  barrier_only();

  f32x16 o[8];                               // full-d partial accumulator (own t-half only)
  #pragma unroll
  for (int di = 0; di < 8; ++di)
    #pragma unroll
    for (int r = 0; r < 16; ++r) o[di][r] = 0.f;

  for (int it = 0; it < 32; ++it) {
    const int cur = it & 1;
    // prefetch next tile into buf[cur^1]; prior readers of that buf finished
    // before the barrier that ended the previous iteration.
    if (it < 31) STAGE_TILE(cur ^ 1, (it + 1) * 64)

    // QK^T as mfma(kf, qf): A rows = t (own half), B cols = s => C col = s, rows = t_local
    const unsigned short* sKc = sK[cur];
    const int tl = tr * 32 + l32;
    f32x16 sacc;
    #pragma unroll
    for (int r = 0; r < 16; ++r) sacc[r] = 0.f;
    __builtin_amdgcn_s_setprio(1);
    #pragma unroll
    for (int kk = 0; kk < 16; ++kk) {
      short8 kf = *(const short8*)(sKc + tl * 256 + (((kk * 2 + half) ^ (tl & 31)) << 3));
      sacc = __builtin_amdgcn_mfma_f32_32x32x16_bf16(kf, qf[kk], sacc, 0, 0, 0);
    }
    __builtin_amdgcn_s_setprio(0);

    // sigmoid, fully in-register (q pre-scaled by 1/16)
    float p[16];
    #pragma unroll
    for (int r = 0; r < 16; ++r)
      p[r] = __builtin_amdgcn_rcpf(1.f + __expf(-sacc[r]));
    if (it == 31 && tr == 1) {               // only the last 7 t-rows are padding
      #pragma unroll
      for (int r = 0; r < 16; ++r) {
        int tloc = (r & 3) + 8 * (r >> 2) + 4 * half;
        if (tloc >= 25) p[r] = 0.f;          // t = 1984+32+tloc >= 2041
      }
    }

    // repack C-frag -> PV B-operand frags for the wave's 2 k-chunks (t_local 0..15, 16..31):
    // lane(h) needs t_local = 8h+e; own regs give {4h..4h+3, 8+4h..}; swap32 exchanges the
    // cross-half words: swap(pk(p0,p1), pk(p4,p5)) -> (e01, e45) valid for BOTH halves.
    short8 pa[2];
    #pragma unroll
    for (int kx = 0; kx < 2; ++kx) {
      unsigned int x0 = cvt_pk_bf16(p[kx * 8 + 0], p[kx * 8 + 1]);
      unsigned int x1 = cvt_pk_bf16(p[kx * 8 + 2], p[kx * 8 + 3]);
      unsigned int y0 = cvt_pk_bf16(p[kx * 8 + 4], p[kx * 8 + 5]);
      unsigned int y1 = cvt_pk_bf16(p[kx * 8 + 6], p[kx * 8 + 7]);
      swap32(x0, y0);
      swap32(x1, y1);
      union { unsigned int u[4]; short8 s; } pu;
      pu.u[0] = x0; pu.u[1] = x1; pu.u[2] = y0; pu.u[3] = y1;
      pa[kx] = pu.s;
    }

    // P·V as mfma(vf, pa): A rows = d (full 256), B cols = s, k = own t-half
    const unsigned short* sVc = sV[cur];
    __builtin_amdgcn_s_setprio(1);
    #pragma unroll
    for (int kx = 0; kx < 2; ++kx) {
      const int c8 = tr * 4 + kx * 2 + half; // global 8-t chunk index within tile
      #pragma unroll
      for (int di = 0; di < 8; ++di) {
        int d = di * 32 + l32;
        short8 vf = *(const short8*)(sVc + d * 64 + ((c8 ^ (d & 7)) << 3));
        o[di] = __builtin_amdgcn_mfma_f32_32x32x16_bf16(vf, pa[kx], o[di], 0, 0, 0);
      }
    }
    __builtin_amdgcn_s_setprio(0);

    if (it < 31) __builtin_amdgcn_s_waitcnt(0x0F70);  // vmcnt(0): next tile landed
    sync_lds();                              // single barrier per iter
  }

  // ---- epilogue: tr-partner reduction via LDS scratch (sK+sV now free) ----
  // wave w sends its partials for the OTHER tr's d-half; layout k*1024 + lane*16
  // (lanes consecutive 16B -> conflict-free b128).
  {
    unsigned short* myreg = (w < 4) ? (&sK[0][0] + (size_t)w * 8192)
                                    : (&sV[0][0] + (size_t)(w - 4) * 8192);
    const int sb = (tr ^ 1) * 4;
    #pragma unroll
    for (int di = 0; di < 4; ++di)
      #pragma unroll
      for (int q = 0; q < 4; ++q) {
        f32x4 v;
        #pragma unroll
        for (int j = 0; j < 4; ++j) v[j] = o[sb + di][q * 4 + j];
        *(f32x4*)((char*)myreg + (di * 4 + q) * 1024 + lane * 16) = v;
      }
  }
  sync_lds();
  {
    const int pw = w ^ 4;
    const unsigned short* preg = (pw < 4) ? (&sK[0][0] + (size_t)pw * 8192)
                                          : (&sV[0][0] + (size_t)(pw - 4) * 8192);
    const int kb_ = tr * 4;                  // d-groups this wave stores
    const int s = s0 + sr * 32 + l32;
    if (s < SL) {
      float* op = out + (size_t)n * CO * SL + s;
      #pragma unroll
      for (int di = 0; di < 4; ++di)
        #pragma unroll
        for (int q = 0; q < 4; ++q) {
          f32x4 v = *(const f32x4*)((const char*)preg + (di * 4 + q) * 1024 + lane * 16);
          #pragma unroll
          for (int j = 0; j < 4; ++j) {
            int r = q * 4 + j;
            int d = (kb_ + di) * 32 + (r & 3) + 8 * (r >> 2) + 4 * half;
            __builtin_nontemporal_store(o[kb_ + di][r] + v[j], op + (size_t)d * SL);
          }
        }
    }
  }
#undef STAGE_TILE
}

extern "C" void kernel_launch(void* const* d_in, const int* in_sizes, int n_in,
                              void* d_out, int out_size, void* d_ws, size_t ws_size,
                              hipStream_t stream) {
  const float* x      = (const float*)d_in[0];
  const float* conv_w = (const float*)d_in[1];
  const float* conv_b = (const float*)d_in[2];
  const float* wq     = (const float*)d_in[3];
  const float* bq     = (const float*)d_in[4];
  const float* wk     = (const float*)d_in[5];
  const float* bk     = (const float*)d_in[6];
  const float* wv     = (const float*)d_in[7];
  const float* bv     = (const float*)d_in[8];

  char* ws = (char*)d_ws;
  unsigned short* xt  = (unsigned short*)(ws + XT_OFF);
  unsigned short* cw  = (unsigned short*)(ws + CW_OFF);
  unsigned short* wqb = (unsigned short*)(ws + WQ_OFF);
  unsigned short* wkb = (unsigned short*)(ws + WK_OFF);
  unsigned short* wvb = (unsigned short*)(ws + WV_OFF);
  unsigned short* hb  = (unsigned short*)(ws + H_OFF);
  unsigned short* qb  = (unsigned short*)(ws + Q_OFF);
  unsigned short* kb  = (unsigned short*)(ws + K_OFF);
  unsigned short* vtb = (unsigned short*)(ws + VT_OFF);

  hipLaunchKernelGGL(xpose_kernel, dim3(64, 4, 16), dim3(32, 8), 0, stream, x, xt);
  hipLaunchKernelGGL(wconv_kernel, dim3(1024), dim3(256), 0, stream, conv_w, cw);
  hipLaunchKernelGGL(wqkv_kernel,  dim3(192), dim3(256), 0, stream,
                     wq, wk, wv, wqb, wkb, wvb);
  hipLaunchKernelGGL(conv_gemm, dim3(16, 16, 2), dim3(256), 0, stream, xt, cw, conv_b, hb);
  hipLaunchKernelGGL(lin_gemm,  dim3(256, 2, 3), dim3(256), 0, stream,
                     hb, wqb, wkb, wvb, bq, bk, bv, qb, kb, vtb);
  hipLaunchKernelGGL(attn_kernel, dim3(256), dim3(512), 0, stream,
                     qb, kb, vtb, (float*)d_out);
}

// Round 2
// 261.289 us; speedup vs baseline: 1.0086x; 1.0086x over previous
//
#include <hip/hip_runtime.h>

typedef short short8 __attribute__((ext_vector_type(8)));
typedef float f32x4 __attribute__((ext_vector_type(4)));
typedef float f32x16 __attribute__((ext_vector_type(16)));
typedef unsigned short u16x4 __attribute__((ext_vector_type(4)));

constexpr int NB = 16, CIN = 128, LIN = 2048, CO = 256;
constexpr int SL = 2041;                 // output sequence length
constexpr int MT = NB * SL;              // 32656 valid rows
constexpr int MP = 32768;                // padded rows
constexpr int XTS = 136;                 // xT row stride (elems): 16B-aligned

// ---- workspace layout (bytes, all 256-aligned) ----
constexpr size_t XT_OFF = 0;
constexpr size_t XT_SZ  = (size_t)NB*LIN*XTS*2 + 65536;  // bf16 xT [n][s][136] + OOB slack
constexpr size_t CW_OFF = XT_OFF + XT_SZ;
constexpr size_t CW_SZ  = (size_t)CO*CIN*8*2;            // conv_w bf16 [256][1024], kk=kp*128+ci
constexpr size_t WQ_OFF = CW_OFF + CW_SZ;
constexpr size_t WB_SZ  = (size_t)CO*CO*2;
constexpr size_t WK_OFF = WQ_OFF + WB_SZ;
constexpr size_t WV_OFF = WK_OFF + WB_SZ;
constexpr size_t H_OFF  = WV_OFF + WB_SZ;
constexpr size_t HB_SZ  = (size_t)MP*CO*2;               // 16 MB each
constexpr size_t Q_OFF  = H_OFF + HB_SZ;
constexpr size_t K_OFF  = Q_OFF + HB_SZ;
constexpr size_t VT_OFF = K_OFF + HB_SZ;                 // v transposed [256][16][2048]

__device__ inline unsigned short f2bf(float f) {
  union { float f; unsigned int u; } v; v.f = f;
  unsigned int r = v.u + 0x7fffu + ((v.u >> 16) & 1u);
  return (unsigned short)(r >> 16);
}

// CK-style LDS barrier: waits only lgkmcnt(0) (ds ops), does NOT drain vmcnt.
__device__ inline void sync_lds() {
  __asm__ volatile("" ::: "memory");
  __builtin_amdgcn_s_waitcnt(0xc07f);   // lgkmcnt(0)
  __builtin_amdgcn_s_barrier();
  __asm__ volatile("" ::: "memory");
}
__device__ inline void barrier_only() {
  __asm__ volatile("" ::: "memory");
  __builtin_amdgcn_s_barrier();
  __asm__ volatile("" ::: "memory");
}

#if defined(__has_builtin)
#if __has_builtin(__builtin_amdgcn_global_load_lds)
#define HAVE_GLDS 1
#endif
#endif

__device__ inline void gld16(const unsigned short* g, void* l) {
#ifdef HAVE_GLDS
  __builtin_amdgcn_global_load_lds(
      (const __attribute__((address_space(1))) void*)g,
      (__attribute__((address_space(3))) void*)l, 16, 0, 0);
#else
  *(short8*)l = *(const short8*)g;
#endif
}

// pack two f32 -> one u32 of 2 bf16 (low = a, high = b); no builtin on gfx950
__device__ inline unsigned int cvt_pk_bf16(float a, float b) {
  unsigned int r;
  asm("v_cvt_pk_bf16_f32 %0, %1, %2" : "=v"(r) : "v"(a), "v"(b));
  return r;
}
// vdst lanes[32:63] <-> vsrc lanes[0:31]; both results used (m214 T12 recipe)
__device__ inline void swap32(unsigned int& a, unsigned int& b) {
  asm("v_permlane32_swap_b32 %0, %1" : "+v"(a), "+v"(b));
}

// ---------------- x transpose + bf16: [16][128][2048] f32 -> [16][2048][136] bf16 ----------------
__global__ void xpose_kernel(const float* __restrict__ x, unsigned short* __restrict__ xt) {
  __shared__ float tile[32][33];
  const int tx = threadIdx.x, ty = threadIdx.y;
  const int s0 = blockIdx.x * 32, c0 = blockIdx.y * 32, n = blockIdx.z;
  #pragma unroll
  for (int r = 0; r < 4; ++r)
    tile[ty * 4 + r][tx] = x[((size_t)(n * CIN + c0 + ty * 4 + r)) * LIN + s0 + tx];
  __syncthreads();
  #pragma unroll
  for (int r = 0; r < 4; ++r)
    xt[((size_t)(n * LIN + s0 + ty * 4 + r)) * XTS + c0 + tx] = f2bf(tile[tx][ty * 4 + r]);
}

// ---------------- conv weight reorder ----------------
__global__ void wconv_kernel(const float* __restrict__ w, unsigned short* __restrict__ o) {
  int idx = blockIdx.x * 256 + threadIdx.x;
  int co = idx >> 10, r = idx & 1023, kp = r >> 7, ci = r & 127;
  o[idx] = f2bf(w[co * 1024 + ci * 8 + kp]);
}

// ---------------- q/k/v weight cvt ----------------
__global__ void wqkv_kernel(const float* __restrict__ a, const float* __restrict__ b,
                            const float* __restrict__ c, unsigned short* __restrict__ oa,
                            unsigned short* __restrict__ ob, unsigned short* __restrict__ oc) {
  int z = blockIdx.x >> 6, lb = blockIdx.x & 63;
  const float* src = (z == 0) ? a : (z == 1) ? b : c;
  unsigned short* dst = (z == 0) ? oa : (z == 1) ? ob : oc;
  int i = (lb * 256 + threadIdx.x) * 4;
  float4 v = *(const float4*)(src + i);
  u16x4 r;
  r.x = f2bf(v.x); r.y = f2bf(v.y); r.z = f2bf(v.z); r.w = f2bf(v.w);
  *(u16x4*)(dst + i) = r;
}

// ---------------- conv as implicit GEMM: reg-prefetch dbuf weights ----------------
__global__ __launch_bounds__(256) void conv_gemm(
    const unsigned short* __restrict__ xt,   // [16][2048][136] bf16
    const unsigned short* __restrict__ wb,   // [256][1024] bf16 (kk = kp*128+ci)
    const float* __restrict__ bias,
    unsigned short* __restrict__ h)          // [MP][256] bf16
{
  __shared__ unsigned short sX[18432];       // 36 KB x-window
  __shared__ unsigned short sB[2][4096];     // 2 x 8 KB weight chunk, chunk-swizzled
  const int tid = threadIdx.x;
  const int w = tid >> 6, lane = tid & 63, quad = lane >> 4, l16 = lane & 15;
  const int n  = blockIdx.y;
  const int s0 = blockIdx.x * 128;
  const int d0 = blockIdx.z * 128;

  {
    const unsigned short* xbase = xt + ((size_t)n * LIN + s0) * XTS;
    #pragma unroll
    for (int i = 0; i < 9; ++i) {
      int u = i * 256 + tid;
      gld16(xbase + u * 8, ((char*)sX) + u * 16);
    }
  }

  const int brow0 = tid >> 2, bkgs = tid & 3;
  short8 breg[2];
  #pragma unroll
  for (int i2 = 0; i2 < 2; ++i2) {
    int row = i2 * 64 + brow0;
    int kg = bkgs ^ ((row >> 1) & 3);
    breg[i2] = *(const short8*)(wb + (size_t)(d0 + row) * 1024 + kg * 8);
  }
  #pragma unroll
  for (int i2 = 0; i2 < 2; ++i2)
    *(short8*)(&sB[0][(i2 * 256 + tid) * 8]) = breg[i2];
  __syncthreads();                          // full drain once (X DMA + sB[0])

  f32x4 acc[2][8];
  #pragma unroll
  for (int i = 0; i < 2; ++i)
    #pragma unroll
    for (int j = 0; j < 8; ++j) acc[i][j] = (f32x4){0.f, 0.f, 0.f, 0.f};

  for (int kc = 0; kc < 32; ++kc) {
    const int kcn = (kc < 31) ? kc + 1 : kc;
    const int kpn = kcn >> 2, ci0n = (kcn & 3) * 32;
    #pragma unroll
    for (int i2 = 0; i2 < 2; ++i2) {
      int row = i2 * 64 + brow0;
      int kg = bkgs ^ ((row >> 1) & 3);
      breg[i2] = *(const short8*)(wb + (size_t)(d0 + row) * 1024 + kpn * 128 + ci0n + kg * 8);
    }

    const int kp = kc >> 2, ci0 = (kc & 3) * 32;
    const unsigned short* sBc = sB[kc & 1];
    short8 bfr[8];
    #pragma unroll
    for (int j = 0; j < 8; ++j) {
      int r = j * 16 + l16;
      bfr[j] = *(const short8*)(sBc + r * 32 + (quad ^ ((r >> 1) & 3)) * 8);
    }
    #pragma unroll
    for (int i = 0; i < 2; ++i) {
      int srow = w * 32 + i * 16 + l16;
      short8 afr = *(const short8*)(sX + (srow + kp) * XTS + ci0 + quad * 8);
      #pragma unroll
      for (int j = 0; j < 8; ++j)
        acc[i][j] = __builtin_amdgcn_mfma_f32_16x16x32_bf16(afr, bfr[j], acc[i][j], 0, 0, 0);
    }

    #pragma unroll
    for (int i2 = 0; i2 < 2; ++i2)
      *(short8*)(&sB[(kc + 1) & 1][(i2 * 256 + tid) * 8]) = breg[i2];
    sync_lds();
  }

  #pragma unroll
  for (int i = 0; i < 2; ++i)
    #pragma unroll
    for (int j = 0; j < 8; ++j) {
      int col = d0 + j * 16 + l16;
      float bv = bias[col];
      #pragma unroll
      for (int jj = 0; jj < 4; ++jj) {
        int s = s0 + w * 32 + i * 16 + quad * 4 + jj;
        if (s < SL) {
          float val = fmaxf(acc[i][j][jj] + bv, 0.f);
          h[(size_t)(n * SL + s) * CO + col] = f2bf(val);
        }
      }
    }
}

// ---------------- q/k/v linear GEMMs: reg-prefetch dbuf A and B ----------------
__global__ __launch_bounds__(256) void lin_gemm(
    const unsigned short* __restrict__ A,    // h [MP][256]
    const unsigned short* __restrict__ Bq, const unsigned short* __restrict__ Bk,
    const unsigned short* __restrict__ Bv,
    const float* __restrict__ biq, const float* __restrict__ bik,
    const float* __restrict__ biv,
    unsigned short* __restrict__ qb, unsigned short* __restrict__ kb,
    unsigned short* __restrict__ vtb)
{
  __shared__ unsigned short sA[2][4096];
  __shared__ unsigned short sB[2][4096];
  const int tid = threadIdx.x;
  const int w = tid >> 6, lane = tid & 63, quad = lane >> 4, l16 = lane & 15;
  const int m0 = blockIdx.x * 128, d0 = blockIdx.y * 128, z = blockIdx.z;
  const unsigned short* B = (z == 0) ? Bq : (z == 1) ? Bk : Bv;
  const float* bias        = (z == 0) ? biq : (z == 1) ? bik : biv;

  const int brow0 = tid >> 2, bkgs = tid & 3;
  short8 areg[2], breg[2];
  #pragma unroll
  for (int i2 = 0; i2 < 2; ++i2) {
    int row = i2 * 64 + brow0;
    int kg = bkgs ^ ((row >> 1) & 3);
    areg[i2] = *(const short8*)(A + (size_t)(m0 + row) * CO + kg * 8);
    breg[i2] = *(const short8*)(B + (size_t)(d0 + row) * CO + kg * 8);
  }
  #pragma unroll
  for (int i2 = 0; i2 < 2; ++i2) {
    *(short8*)(&sA[0][(i2 * 256 + tid) * 8]) = areg[i2];
    *(short8*)(&sB[0][(i2 * 256 + tid) * 8]) = breg[i2];
  }
  sync_lds();

  f32x4 acc[2][8];
  #pragma unroll
  for (int i = 0; i < 2; ++i)
    #pragma unroll
    for (int j = 0; j < 8; ++j) acc[i][j] = (f32x4){0.f, 0.f, 0.f, 0.f};

  for (int kc = 0; kc < 8; ++kc) {
    const int kcn = (kc < 7) ? kc + 1 : kc;
    #pragma unroll
    for (int i2 = 0; i2 < 2; ++i2) {
      int row = i2 * 64 + brow0;
      int kg = bkgs ^ ((row >> 1) & 3);
      areg[i2] = *(const short8*)(A + (size_t)(m0 + row) * CO + kcn * 32 + kg * 8);
      breg[i2] = *(const short8*)(B + (size_t)(d0 + row) * CO + kcn * 32 + kg * 8);
    }

    const unsigned short* sAc = sA[kc & 1];
    const unsigned short* sBc = sB[kc & 1];
    short8 afr[2], bfr[8];
    #pragma unroll
    for (int i = 0; i < 2; ++i) {
      int r = w * 32 + i * 16 + l16;
      afr[i] = *(const short8*)(sAc + r * 32 + (quad ^ ((r >> 1) & 3)) * 8);
    }
    #pragma unroll
    for (int j = 0; j < 8; ++j) {
      int r = j * 16 + l16;
      bfr[j] = *(const short8*)(sBc + r * 32 + (quad ^ ((r >> 1) & 3)) * 8);
    }
    #pragma unroll
    for (int i = 0; i < 2; ++i)
      #pragma unroll
      for (int j = 0; j < 8; ++j)
        acc[i][j] = __builtin_amdgcn_mfma_f32_16x16x32_bf16(afr[i], bfr[j], acc[i][j], 0, 0, 0);

    #pragma unroll
    for (int i2 = 0; i2 < 2; ++i2) {
      *(short8*)(&sA[(kc + 1) & 1][(i2 * 256 + tid) * 8]) = areg[i2];
      *(short8*)(&sB[(kc + 1) & 1][(i2 * 256 + tid) * 8]) = breg[i2];
    }
    sync_lds();
  }

  #pragma unroll
  for (int i = 0; i < 2; ++i)
    #pragma unroll
    for (int j = 0; j < 8; ++j) {
      int col = d0 + j * 16 + l16;
      float bv = bias[col];
      #pragma unroll
      for (int jj = 0; jj < 4; ++jj) {
        int m = m0 + w * 32 + i * 16 + quad * 4 + jj;
        float val = acc[i][j][jj] + bv;
        if (z == 0) {
          // fold the attention 1/sqrt(C)=1/16 score scale into q (exact pow2 in bf16)
          qb[(size_t)m * CO + col] = f2bf(val * 0.0625f);
        } else if (z == 1) {
          kb[(size_t)m * CO + col] = f2bf(val);
        } else if (m < MT) {
          int nn = m / SL, ss = m - nn * SL;
          vtb[(size_t)col * MP + nn * 2048 + ss] = f2bf(val);
        }
      }
    }
}

// ---------------- fused sigmoid attention: in-register P (T12), 1 barrier/iter ---------------
// grid 256, 512 threads = 8 waves (sr=w&3 s-range, tr=w>>2 t-half), s-tile 128, t-tile 64.
// LDS (128 KB): sK[2]: [64 t][32 slots x 16B] XOR-slot; sV[2]: [256 d][8 slots x 16B] XOR-slot.
// P never touches LDS: QK C-frag -> sigmoid IN PLACE on sacc -> cvt_pk_bf16 pairs ->
// permlane32_swap -> PV B-operand frags. Each wave owns its t-half of P, PV accumulates a
// FULL-d (256) partial o[8]; tr-partners sum via LDS scratch at epilogue.
// Register budget note (round-1 post-mortem): 512-thr block => 2 waves/SIMD => 256 regs HARD.
// o[8]=128 (AGPR) + qf=64 + sacc=16 + pa=8 + temps must stay < 128 VGPR-side. The separate
// p[16] array in round 1 pushed past the cap -> in-loop scratch spill (WRITE_SIZE 41->172MB).
__global__ __launch_bounds__(512, 2) void attn_kernel(
    const unsigned short* __restrict__ qb,   // [MP][256] (pre-scaled by 1/16)
    const unsigned short* __restrict__ kb,   // [MP][256]
    const unsigned short* __restrict__ vtb,  // [256][16][2048]
    float* __restrict__ out)                 // [16][256][2041]
{
  __shared__ unsigned short sK[2][16384];    // 2 x 32 KB
  __shared__ unsigned short sV[2][16384];    // 2 x 32 KB
  const int tid = threadIdx.x;
  const int w = tid >> 6, lane = tid & 63;
  const int half = lane >> 5, l32 = lane & 31;
  const int bidx = blockIdx.x;
  const int n = (bidx & 7) + ((bidx >> 7) << 3);   // XCD-pinned: 2 n's per XCD
  const int s0 = ((bidx >> 3) & 15) * 128;
  const int sr = w & 3, tr = w >> 2;         // tr = t-half owned in QK/P

  const unsigned short* kbN = kb + (size_t)(n * SL) * CO;
  const unsigned short* vbN = vtb + (size_t)n * 2048;

  // K: u = i*512+tid -> t = u>>5, slot = u&31; cell holds global chunk slot^(t&31).
  // V: u -> d = u>>3, slot = u&7; cell holds global t-chunk slot^(d&7).
#define STAGE_TILE(buf, tk)                                                      \
  {                                                                              \
    _Pragma("unroll")                                                            \
    for (int i = 0; i < 4; ++i) {                                                \
      int u = i * 512 + tid;                                                     \
      int t = u >> 5, sl = u & 31;                                               \
      gld16(kbN + (size_t)((tk) + t) * CO + ((sl ^ (t & 31)) << 3),              \
            ((char*)sK[buf]) + u * 16);                                          \
    }                                                                            \
    _Pragma("unroll")                                                            \
    for (int i = 0; i < 4; ++i) {                                                \
      int u = i * 512 + tid;                                                     \
      int d = u >> 3, sl = u & 7;                                                \
      gld16(vbN + (size_t)d * MP + (tk) + ((sl ^ (d & 7)) << 3),                 \
            ((char*)sV[buf]) + u * 16);                                          \
    }                                                                            \
  }

  STAGE_TILE(0, 0)

  // Q frags (B-operand): element (s = s0+sr*32+l32, c = kk*16+half*8+j)
  short8 qf[16];
  {
    const unsigned short* qp = qb + (size_t)(n * SL + s0 + sr * 32 + l32) * CO + half * 8;
    #pragma unroll
    for (int kk = 0; kk < 16; ++kk) qf[kk] = *(const short8*)(qp + kk * 16);
  }

  __builtin_amdgcn_s_waitcnt(0x0F70);        // vmcnt(0): tile0 + Q resident
  barrier_only();

  f32x16 o[8];                               // full-d partial accumulator (own t-half only)
  #pragma unroll
  for (int di = 0; di < 8; ++di)
    #pragma unroll
    for (int r = 0; r < 16; ++r) o[di][r] = 0.f;

  for (int it = 0; it < 32; ++it) {
    const int cur = it & 1;
    // prefetch next tile into buf[cur^1]; prior readers of that buf finished
    // before the barrier that ended the previous iteration.
    if (it < 31) STAGE_TILE(cur ^ 1, (it + 1) * 64)

    // QK^T as mfma(kf, qf): A rows = t (own half), B cols = s => C col = s, rows = t_local
    const unsigned short* sKc = sK[cur];
    const int tl = tr * 32 + l32;
    f32x16 sacc;
    #pragma unroll
    for (int r = 0; r < 16; ++r) sacc[r] = 0.f;
    __builtin_amdgcn_s_setprio(1);
    #pragma unroll
    for (int kk = 0; kk < 16; ++kk) {
      short8 kf = *(const short8*)(sKc + tl * 256 + (((kk * 2 + half) ^ (tl & 31)) << 3));
      sacc = __builtin_amdgcn_mfma_f32_32x32x16_bf16(kf, qf[kk], sacc, 0, 0, 0);
    }
    __builtin_amdgcn_s_setprio(0);

    // sigmoid IN PLACE (q pre-scaled by 1/16) -- no separate p[] array (reg diet)
    #pragma unroll
    for (int r = 0; r < 16; ++r)
      sacc[r] = __builtin_amdgcn_rcpf(1.f + __expf(-sacc[r]));
    if (it == 31 && tr == 1) {               // only the last 7 t-rows are padding
      #pragma unroll
      for (int r = 0; r < 16; ++r) {
        int tloc = (r & 3) + 8 * (r >> 2) + 4 * half;
        if (tloc >= 25) sacc[r] = 0.f;       // t = 1984+32+tloc >= 2041
      }
    }

    // repack C-frag -> PV B-operand frags for the wave's 2 k-chunks (t_local 0..15, 16..31):
    // lane(h) needs t_local = 8h+e; own regs give {4h..4h+3, 8+4h..}; swap32 exchanges the
    // cross-half words: swap(pk(p0,p1), pk(p4,p5)) -> (e01, e45) valid for BOTH halves.
    short8 pa[2];
    #pragma unroll
    for (int kx = 0; kx < 2; ++kx) {
      unsigned int x0 = cvt_pk_bf16(sacc[kx * 8 + 0], sacc[kx * 8 + 1]);
      unsigned int x1 = cvt_pk_bf16(sacc[kx * 8 + 2], sacc[kx * 8 + 3]);
      unsigned int y0 = cvt_pk_bf16(sacc[kx * 8 + 4], sacc[kx * 8 + 5]);
      unsigned int y1 = cvt_pk_bf16(sacc[kx * 8 + 6], sacc[kx * 8 + 7]);
      swap32(x0, y0);
      swap32(x1, y1);
      union { unsigned int u[4]; short8 s; } pu;
      pu.u[0] = x0; pu.u[1] = x1; pu.u[2] = y0; pu.u[3] = y1;
      pa[kx] = pu.s;
    }

    // P·V as mfma(vf, pa): A rows = d (full 256), B cols = s, k = own t-half
    const unsigned short* sVc = sV[cur];
    __builtin_amdgcn_s_setprio(1);
    #pragma unroll
    for (int kx = 0; kx < 2; ++kx) {
      const int c8 = tr * 4 + kx * 2 + half; // global 8-t chunk index within tile
      #pragma unroll
      for (int di = 0; di < 8; ++di) {
        int d = di * 32 + l32;
        short8 vf = *(const short8*)(sVc + d * 64 + ((c8 ^ (d & 7)) << 3));
        o[di] = __builtin_amdgcn_mfma_f32_32x32x16_bf16(vf, pa[kx], o[di], 0, 0, 0);
      }
    }
    __builtin_amdgcn_s_setprio(0);

    if (it < 31) __builtin_amdgcn_s_waitcnt(0x0F70);  // vmcnt(0): next tile landed
    sync_lds();                              // single barrier per iter
  }

  // ---- epilogue: tr-partner reduction via LDS scratch (sK+sV now free) ----
  // wave w sends its partials for the OTHER tr's d-half; layout k*1024 + lane*16
  // (lanes consecutive 16B -> conflict-free b128).
  {
    unsigned short* myreg = (w < 4) ? (&sK[0][0] + (size_t)w * 8192)
                                    : (&sV[0][0] + (size_t)(w - 4) * 8192);
    const int sb = (tr ^ 1) * 4;
    #pragma unroll
    for (int di = 0; di < 4; ++di)
      #pragma unroll
      for (int q = 0; q < 4; ++q) {
        f32x4 v;
        #pragma unroll
        for (int j = 0; j < 4; ++j) v[j] = o[sb + di][q * 4 + j];
        *(f32x4*)((char*)myreg + (di * 4 + q) * 1024 + lane * 16) = v;
      }
  }
  sync_lds();
  {
    const int pw = w ^ 4;
    const unsigned short* preg = (pw < 4) ? (&sK[0][0] + (size_t)pw * 8192)
                                          : (&sV[0][0] + (size_t)(pw - 4) * 8192);
    const int kb_ = tr * 4;                  // d-groups this wave stores
    const int s = s0 + sr * 32 + l32;
    if (s < SL) {
      float* op = out + (size_t)n * CO * SL + s;
      #pragma unroll
      for (int di = 0; di < 4; ++di)
        #pragma unroll
        for (int q = 0; q < 4; ++q) {
          f32x4 v = *(const f32x4*)((const char*)preg + (di * 4 + q) * 1024 + lane * 16);
          #pragma unroll
          for (int j = 0; j < 4; ++j) {
            int r = q * 4 + j;
            int d = (kb_ + di) * 32 + (r & 3) + 8 * (r >> 2) + 4 * half;
            __builtin_nontemporal_store(o[kb_ + di][r] + v[j], op + (size_t)d * SL);
          }
        }
    }
  }
#undef STAGE_TILE
}

extern "C" void kernel_launch(void* const* d_in, const int* in_sizes, int n_in,
                              void* d_out, int out_size, void* d_ws, size_t ws_size,
                              hipStream_t stream) {
  const float* x      = (const float*)d_in[0];
  const float* conv_w = (const float*)d_in[1];
  const float* conv_b = (const float*)d_in[2];
  const float* wq     = (const float*)d_in[3];
  const float* bq     = (const float*)d_in[4];
  const float* wk     = (const float*)d_in[5];
  const float* bk     = (const float*)d_in[6];
  const float* wv     = (const float*)d_in[7];
  const float* bv     = (const float*)d_in[8];

  char* ws = (char*)d_ws;
  unsigned short* xt  = (unsigned short*)(ws + XT_OFF);
  unsigned short* cw  = (unsigned short*)(ws + CW_OFF);
  unsigned short* wqb = (unsigned short*)(ws + WQ_OFF);
  unsigned short* wkb = (unsigned short*)(ws + WK_OFF);
  unsigned short* wvb = (unsigned short*)(ws + WV_OFF);
  unsigned short* hb  = (unsigned short*)(ws + H_OFF);
  unsigned short* qb  = (unsigned short*)(ws + Q_OFF);
  unsigned short* kb  = (unsigned short*)(ws + K_OFF);
  unsigned short* vtb = (unsigned short*)(ws + VT_OFF);

  hipLaunchKernelGGL(xpose_kernel, dim3(64, 4, 16), dim3(32, 8), 0, stream, x, xt);
  hipLaunchKernelGGL(wconv_kernel, dim3(1024), dim3(256), 0, stream, conv_w, cw);
  hipLaunchKernelGGL(wqkv_kernel,  dim3(192), dim3(256), 0, stream,
                     wq, wk, wv, wqb, wkb, wvb);
  hipLaunchKernelGGL(conv_gemm, dim3(16, 16, 2), dim3(256), 0, stream, xt, cw, conv_b, hb);
  hipLaunchKernelGGL(lin_gemm,  dim3(256, 2, 3), dim3(256), 0, stream,
                     hb, wqb, wkb, wvb, bq, bk, bv, qb, kb, vtb);
  hipLaunchKernelGGL(attn_kernel, dim3(256), dim3(512), 0, stream,
                     qb, kb, vtb, (float*)d_out);
}

// Round 3
// 259.260 us; speedup vs baseline: 1.0165x; 1.0078x over previous
//
#include <hip/hip_runtime.h>

typedef short short8 __attribute__((ext_vector_type(8)));
typedef float f32x4 __attribute__((ext_vector_type(4)));
typedef float f32x16 __attribute__((ext_vector_type(16)));
typedef unsigned short u16x4 __attribute__((ext_vector_type(4)));

constexpr int NB = 16, CIN = 128, LIN = 2048, CO = 256;
constexpr int SL = 2041;                 // output sequence length
constexpr int MT = NB * SL;              // 32656 valid rows
constexpr int MP = 32768;                // padded rows
constexpr int XTS = 136;                 // xT row stride (elems): 16B-aligned

// ---- workspace layout (bytes, all 256-aligned) ----
constexpr size_t XT_OFF = 0;
constexpr size_t XT_SZ  = (size_t)NB*LIN*XTS*2 + 65536;  // bf16 xT [n][s][136] + OOB slack
constexpr size_t CW_OFF = XT_OFF + XT_SZ;
constexpr size_t CW_SZ  = (size_t)CO*CIN*8*2;            // conv_w bf16 [256][1024], kk=kp*128+ci
constexpr size_t WQ_OFF = CW_OFF + CW_SZ;
constexpr size_t WB_SZ  = (size_t)CO*CO*2;
constexpr size_t WK_OFF = WQ_OFF + WB_SZ;
constexpr size_t WV_OFF = WK_OFF + WB_SZ;
constexpr size_t H_OFF  = WV_OFF + WB_SZ;
constexpr size_t HB_SZ  = (size_t)MP*CO*2;               // 16 MB each
constexpr size_t Q_OFF  = H_OFF + HB_SZ;
constexpr size_t K_OFF  = Q_OFF + HB_SZ;
constexpr size_t VT_OFF = K_OFF + HB_SZ;                 // v transposed [256][16][2048]

__device__ inline unsigned short f2bf(float f) {
  union { float f; unsigned int u; } v; v.f = f;
  unsigned int r = v.u + 0x7fffu + ((v.u >> 16) & 1u);
  return (unsigned short)(r >> 16);
}

// CK-style LDS barrier: waits only lgkmcnt(0) (ds ops), does NOT drain vmcnt.
__device__ inline void sync_lds() {
  __asm__ volatile("" ::: "memory");
  __builtin_amdgcn_s_waitcnt(0xc07f);   // lgkmcnt(0)
  __builtin_amdgcn_s_barrier();
  __asm__ volatile("" ::: "memory");
}
__device__ inline void barrier_only() {
  __asm__ volatile("" ::: "memory");
  __builtin_amdgcn_s_barrier();
  __asm__ volatile("" ::: "memory");
}

#if defined(__has_builtin)
#if __has_builtin(__builtin_amdgcn_global_load_lds)
#define HAVE_GLDS 1
#endif
#endif

__device__ inline void gld16(const unsigned short* g, void* l) {
#ifdef HAVE_GLDS
  __builtin_amdgcn_global_load_lds(
      (const __attribute__((address_space(1))) void*)g,
      (__attribute__((address_space(3))) void*)l, 16, 0, 0);
#else
  *(short8*)l = *(const short8*)g;
#endif
}

// pack two f32 -> one u32 of 2 bf16 (low = a, high = b); no builtin on gfx950
__device__ inline unsigned int cvt_pk_bf16(float a, float b) {
  unsigned int r;
  asm("v_cvt_pk_bf16_f32 %0, %1, %2" : "=v"(r) : "v"(a), "v"(b));
  return r;
}
// vdst lanes[32:63] <-> vsrc lanes[0:31]; both results used (m214 T12 recipe)
__device__ inline void swap32(unsigned int& a, unsigned int& b) {
  asm("v_permlane32_swap_b32 %0, %1" : "+v"(a), "+v"(b));
}

// ---------------- x transpose + bf16: [16][128][2048] f32 -> [16][2048][136] bf16 ----------------
__global__ void xpose_kernel(const float* __restrict__ x, unsigned short* __restrict__ xt) {
  __shared__ float tile[32][33];
  const int tx = threadIdx.x, ty = threadIdx.y;
  const int s0 = blockIdx.x * 32, c0 = blockIdx.y * 32, n = blockIdx.z;
  #pragma unroll
  for (int r = 0; r < 4; ++r)
    tile[ty * 4 + r][tx] = x[((size_t)(n * CIN + c0 + ty * 4 + r)) * LIN + s0 + tx];
  __syncthreads();
  #pragma unroll
  for (int r = 0; r < 4; ++r)
    xt[((size_t)(n * LIN + s0 + ty * 4 + r)) * XTS + c0 + tx] = f2bf(tile[tx][ty * 4 + r]);
}

// ---------------- conv weight reorder ----------------
__global__ void wconv_kernel(const float* __restrict__ w, unsigned short* __restrict__ o) {
  int idx = blockIdx.x * 256 + threadIdx.x;
  int co = idx >> 10, r = idx & 1023, kp = r >> 7, ci = r & 127;
  o[idx] = f2bf(w[co * 1024 + ci * 8 + kp]);
}

// ---------------- q/k/v weight cvt ----------------
__global__ void wqkv_kernel(const float* __restrict__ a, const float* __restrict__ b,
                            const float* __restrict__ c, unsigned short* __restrict__ oa,
                            unsigned short* __restrict__ ob, unsigned short* __restrict__ oc) {
  int z = blockIdx.x >> 6, lb = blockIdx.x & 63;
  const float* src = (z == 0) ? a : (z == 1) ? b : c;
  unsigned short* dst = (z == 0) ? oa : (z == 1) ? ob : oc;
  int i = (lb * 256 + threadIdx.x) * 4;
  float4 v = *(const float4*)(src + i);
  u16x4 r;
  r.x = f2bf(v.x); r.y = f2bf(v.y); r.z = f2bf(v.z); r.w = f2bf(v.w);
  *(u16x4*)(dst + i) = r;
}

// ---------------- conv as implicit GEMM: reg-prefetch dbuf weights ----------------
__global__ __launch_bounds__(256) void conv_gemm(
    const unsigned short* __restrict__ xt,   // [16][2048][136] bf16
    const unsigned short* __restrict__ wb,   // [256][1024] bf16 (kk = kp*128+ci)
    const float* __restrict__ bias,
    unsigned short* __restrict__ h)          // [MP][256] bf16
{
  __shared__ unsigned short sX[18432];       // 36 KB x-window
  __shared__ unsigned short sB[2][4096];     // 2 x 8 KB weight chunk, chunk-swizzled
  const int tid = threadIdx.x;
  const int w = tid >> 6, lane = tid & 63, quad = lane >> 4, l16 = lane & 15;
  const int n  = blockIdx.y;
  const int s0 = blockIdx.x * 128;
  const int d0 = blockIdx.z * 128;

  {
    const unsigned short* xbase = xt + ((size_t)n * LIN + s0) * XTS;
    #pragma unroll
    for (int i = 0; i < 9; ++i) {
      int u = i * 256 + tid;
      gld16(xbase + u * 8, ((char*)sX) + u * 16);
    }
  }

  const int brow0 = tid >> 2, bkgs = tid & 3;
  short8 breg[2];
  #pragma unroll
  for (int i2 = 0; i2 < 2; ++i2) {
    int row = i2 * 64 + brow0;
    int kg = bkgs ^ ((row >> 1) & 3);
    breg[i2] = *(const short8*)(wb + (size_t)(d0 + row) * 1024 + kg * 8);
  }
  #pragma unroll
  for (int i2 = 0; i2 < 2; ++i2)
    *(short8*)(&sB[0][(i2 * 256 + tid) * 8]) = breg[i2];
  __syncthreads();                          // full drain once (X DMA + sB[0])

  f32x4 acc[2][8];
  #pragma unroll
  for (int i = 0; i < 2; ++i)
    #pragma unroll
    for (int j = 0; j < 8; ++j) acc[i][j] = (f32x4){0.f, 0.f, 0.f, 0.f};

  for (int kc = 0; kc < 32; ++kc) {
    const int kcn = (kc < 31) ? kc + 1 : kc;
    const int kpn = kcn >> 2, ci0n = (kcn & 3) * 32;
    #pragma unroll
    for (int i2 = 0; i2 < 2; ++i2) {
      int row = i2 * 64 + brow0;
      int kg = bkgs ^ ((row >> 1) & 3);
      breg[i2] = *(const short8*)(wb + (size_t)(d0 + row) * 1024 + kpn * 128 + ci0n + kg * 8);
    }

    const int kp = kc >> 2, ci0 = (kc & 3) * 32;
    const unsigned short* sBc = sB[kc & 1];
    short8 bfr[8];
    #pragma unroll
    for (int j = 0; j < 8; ++j) {
      int r = j * 16 + l16;
      bfr[j] = *(const short8*)(sBc + r * 32 + (quad ^ ((r >> 1) & 3)) * 8);
    }
    #pragma unroll
    for (int i = 0; i < 2; ++i) {
      int srow = w * 32 + i * 16 + l16;
      short8 afr = *(const short8*)(sX + (srow + kp) * XTS + ci0 + quad * 8);
      #pragma unroll
      for (int j = 0; j < 8; ++j)
        acc[i][j] = __builtin_amdgcn_mfma_f32_16x16x32_bf16(afr, bfr[j], acc[i][j], 0, 0, 0);
    }

    #pragma unroll
    for (int i2 = 0; i2 < 2; ++i2)
      *(short8*)(&sB[(kc + 1) & 1][(i2 * 256 + tid) * 8]) = breg[i2];
    sync_lds();
  }

  #pragma unroll
  for (int i = 0; i < 2; ++i)
    #pragma unroll
    for (int j = 0; j < 8; ++j) {
      int col = d0 + j * 16 + l16;
      float bv = bias[col];
      #pragma unroll
      for (int jj = 0; jj < 4; ++jj) {
        int s = s0 + w * 32 + i * 16 + quad * 4 + jj;
        if (s < SL) {
          float val = fmaxf(acc[i][j][jj] + bv, 0.f);
          h[(size_t)(n * SL + s) * CO + col] = f2bf(val);
        }
      }
    }
}

// ---------------- q/k/v linear GEMMs: reg-prefetch dbuf A and B ----------------
__global__ __launch_bounds__(256) void lin_gemm(
    const unsigned short* __restrict__ A,    // h [MP][256]
    const unsigned short* __restrict__ Bq, const unsigned short* __restrict__ Bk,
    const unsigned short* __restrict__ Bv,
    const float* __restrict__ biq, const float* __restrict__ bik,
    const float* __restrict__ biv,
    unsigned short* __restrict__ qb, unsigned short* __restrict__ kb,
    unsigned short* __restrict__ vtb)
{
  __shared__ unsigned short sA[2][4096];
  __shared__ unsigned short sB[2][4096];
  const int tid = threadIdx.x;
  const int w = tid >> 6, lane = tid & 63, quad = lane >> 4, l16 = lane & 15;
  const int m0 = blockIdx.x * 128, d0 = blockIdx.y * 128, z = blockIdx.z;
  const unsigned short* B = (z == 0) ? Bq : (z == 1) ? Bk : Bv;
  const float* bias        = (z == 0) ? biq : (z == 1) ? bik : biv;

  const int brow0 = tid >> 2, bkgs = tid & 3;
  short8 areg[2], breg[2];
  #pragma unroll
  for (int i2 = 0; i2 < 2; ++i2) {
    int row = i2 * 64 + brow0;
    int kg = bkgs ^ ((row >> 1) & 3);
    areg[i2] = *(const short8*)(A + (size_t)(m0 + row) * CO + kg * 8);
    breg[i2] = *(const short8*)(B + (size_t)(d0 + row) * CO + kg * 8);
  }
  #pragma unroll
  for (int i2 = 0; i2 < 2; ++i2) {
    *(short8*)(&sA[0][(i2 * 256 + tid) * 8]) = areg[i2];
    *(short8*)(&sB[0][(i2 * 256 + tid) * 8]) = breg[i2];
  }
  sync_lds();

  f32x4 acc[2][8];
  #pragma unroll
  for (int i = 0; i < 2; ++i)
    #pragma unroll
    for (int j = 0; j < 8; ++j) acc[i][j] = (f32x4){0.f, 0.f, 0.f, 0.f};

  for (int kc = 0; kc < 8; ++kc) {
    const int kcn = (kc < 7) ? kc + 1 : kc;
    #pragma unroll
    for (int i2 = 0; i2 < 2; ++i2) {
      int row = i2 * 64 + brow0;
      int kg = bkgs ^ ((row >> 1) & 3);
      areg[i2] = *(const short8*)(A + (size_t)(m0 + row) * CO + kcn * 32 + kg * 8);
      breg[i2] = *(const short8*)(B + (size_t)(d0 + row) * CO + kcn * 32 + kg * 8);
    }

    const unsigned short* sAc = sA[kc & 1];
    const unsigned short* sBc = sB[kc & 1];
    short8 afr[2], bfr[8];
    #pragma unroll
    for (int i = 0; i < 2; ++i) {
      int r = w * 32 + i * 16 + l16;
      afr[i] = *(const short8*)(sAc + r * 32 + (quad ^ ((r >> 1) & 3)) * 8);
    }
    #pragma unroll
    for (int j = 0; j < 8; ++j) {
      int r = j * 16 + l16;
      bfr[j] = *(const short8*)(sBc + r * 32 + (quad ^ ((r >> 1) & 3)) * 8);
    }
    #pragma unroll
    for (int i = 0; i < 2; ++i)
      #pragma unroll
      for (int j = 0; j < 8; ++j)
        acc[i][j] = __builtin_amdgcn_mfma_f32_16x16x32_bf16(afr[i], bfr[j], acc[i][j], 0, 0, 0);

    #pragma unroll
    for (int i2 = 0; i2 < 2; ++i2) {
      *(short8*)(&sA[(kc + 1) & 1][(i2 * 256 + tid) * 8]) = areg[i2];
      *(short8*)(&sB[(kc + 1) & 1][(i2 * 256 + tid) * 8]) = breg[i2];
    }
    sync_lds();
  }

  #pragma unroll
  for (int i = 0; i < 2; ++i)
    #pragma unroll
    for (int j = 0; j < 8; ++j) {
      int col = d0 + j * 16 + l16;
      float bv = bias[col];
      #pragma unroll
      for (int jj = 0; jj < 4; ++jj) {
        int m = m0 + w * 32 + i * 16 + quad * 4 + jj;
        float val = acc[i][j][jj] + bv;
        if (z == 0) {
          // fold the attention 1/sqrt(C)=1/16 score scale into q (exact pow2 in bf16)
          qb[(size_t)m * CO + col] = f2bf(val * 0.0625f);
        } else if (z == 1) {
          kb[(size_t)m * CO + col] = f2bf(val);
        } else if (m < MT) {
          int nn = m / SL, ss = m - nn * SL;
          vtb[(size_t)col * MP + nn * 2048 + ss] = f2bf(val);
        }
      }
    }
}

// ---------------- fused sigmoid attention: 4-wave block, 512-reg budget, in-reg P ----------
// Round-2 post-mortem: a 512-thr block caps each wave at 256 regs (2048/lane-slot per CU,
// 2 waves/SIMD) -> o[8]+qf[16] structurally spilled (WRITE_SIZE 172 MB). Fix the SHAPE:
// 256 threads = 4 waves = 1 wave/SIMD -> 512-reg budget, everything fits.
// Each wave: one 32-wide s-range (sr=w), FULL 64-t tile (th=0,1 halves), full d=256.
// Per iter per wave: 2x(16 QK MFMA + 16 PV MFMA) -- zero duplication, o complete at end,
// NO epilogue partner-exchange. LDS unchanged: sK[2] 64tx256c XOR-slot, sV[2] 256dx64t.
__global__ __launch_bounds__(256, 1) void attn_kernel(
    const unsigned short* __restrict__ qb,   // [MP][256] (pre-scaled by 1/16)
    const unsigned short* __restrict__ kb,   // [MP][256]
    const unsigned short* __restrict__ vtb,  // [256][16][2048]
    float* __restrict__ out)                 // [16][256][2041]
{
  __shared__ unsigned short sK[2][16384];    // 2 x 32 KB
  __shared__ unsigned short sV[2][16384];    // 2 x 32 KB
  const int tid = threadIdx.x;
  const int w = tid >> 6, lane = tid & 63;
  const int half = lane >> 5, l32 = lane & 31;
  const int bidx = blockIdx.x;
  const int n = (bidx & 7) + ((bidx >> 7) << 3);   // XCD-pinned: 2 n's per XCD
  const int s0 = ((bidx >> 3) & 15) * 128;

  const unsigned short* kbN = kb + (size_t)(n * SL) * CO;
  const unsigned short* vbN = vtb + (size_t)n * 2048;

  // K: u = i*256+tid -> t = u>>5, slot = u&31; cell holds global c-chunk slot^(t&31).
  // V: u -> d = u>>3, slot = u&7; cell holds global t-chunk slot^(d&7).
#define STAGE_TILE(buf, tk)                                                      \
  {                                                                              \
    _Pragma("unroll")                                                            \
    for (int i = 0; i < 8; ++i) {                                                \
      int u = i * 256 + tid;                                                     \
      int t = u >> 5, sl = u & 31;                                               \
      gld16(kbN + (size_t)((tk) + t) * CO + ((sl ^ (t & 31)) << 3),              \
            ((char*)sK[buf]) + u * 16);                                          \
    }                                                                            \
    _Pragma("unroll")                                                            \
    for (int i = 0; i < 8; ++i) {                                                \
      int u = i * 256 + tid;                                                     \
      int d = u >> 3, sl = u & 7;                                                \
      gld16(vbN + (size_t)d * MP + (tk) + ((sl ^ (d & 7)) << 3),                 \
            ((char*)sV[buf]) + u * 16);                                          \
    }                                                                            \
  }

  STAGE_TILE(0, 0)

  // Q frags (B-operand): element (s = s0+w*32+l32, c = kk*16+half*8+j)
  short8 qf[16];
  {
    const unsigned short* qp = qb + (size_t)(n * SL + s0 + w * 32 + l32) * CO + half * 8;
    #pragma unroll
    for (int kk = 0; kk < 16; ++kk) qf[kk] = *(const short8*)(qp + kk * 16);
  }

  __builtin_amdgcn_s_waitcnt(0x0F70);        // vmcnt(0): tile0 + Q resident
  barrier_only();

  f32x16 o[8];                               // full-d accumulator (complete: all t summed here)
  #pragma unroll
  for (int di = 0; di < 8; ++di)
    #pragma unroll
    for (int r = 0; r < 16; ++r) o[di][r] = 0.f;

  for (int it = 0; it < 32; ++it) {
    const int cur = it & 1;
    // prefetch next tile into buf[cur^1]; prior readers of that buf finished
    // before the barrier that ended the previous iteration.
    if (it < 31) STAGE_TILE(cur ^ 1, (it + 1) * 64)

    const unsigned short* sKc = sK[cur];
    const unsigned short* sVc = sV[cur];

    #pragma unroll
    for (int th = 0; th < 2; ++th) {
      // QK^T as mfma(kf, qf): A rows = t (half th), B cols = s => C col = s, rows = t_local
      const int tl = th * 32 + l32;
      f32x16 sacc;
      #pragma unroll
      for (int r = 0; r < 16; ++r) sacc[r] = 0.f;
      __builtin_amdgcn_s_setprio(1);
      #pragma unroll
      for (int kk = 0; kk < 16; ++kk) {
        short8 kf = *(const short8*)(sKc + tl * 256 + (((kk * 2 + half) ^ (tl & 31)) << 3));
        sacc = __builtin_amdgcn_mfma_f32_32x32x16_bf16(kf, qf[kk], sacc, 0, 0, 0);
      }
      __builtin_amdgcn_s_setprio(0);

      // sigmoid in place (q pre-scaled by 1/16)
      #pragma unroll
      for (int r = 0; r < 16; ++r)
        sacc[r] = __builtin_amdgcn_rcpf(1.f + __expf(-sacc[r]));
      if (it == 31 && th == 1) {             // only the last 7 t-rows are padding
        #pragma unroll
        for (int r = 0; r < 16; ++r) {
          int tloc = (r & 3) + 8 * (r >> 2) + 4 * half;
          if (tloc >= 25) sacc[r] = 0.f;     // t = 1984+32+tloc >= 2041
        }
      }

      // repack C-frag -> PV B-operand frags (t_local kx*8..kx*8+7 within this half):
      // lane(h) needs t_local = 8h+e; swap32 exchanges the cross-half words.
      short8 pa[2];
      #pragma unroll
      for (int kx = 0; kx < 2; ++kx) {
        unsigned int x0 = cvt_pk_bf16(sacc[kx * 8 + 0], sacc[kx * 8 + 1]);
        unsigned int x1 = cvt_pk_bf16(sacc[kx * 8 + 2], sacc[kx * 8 + 3]);
        unsigned int y0 = cvt_pk_bf16(sacc[kx * 8 + 4], sacc[kx * 8 + 5]);
        unsigned int y1 = cvt_pk_bf16(sacc[kx * 8 + 6], sacc[kx * 8 + 7]);
        swap32(x0, y0);
        swap32(x1, y1);
        union { unsigned int u[4]; short8 s; } pu;
        pu.u[0] = x0; pu.u[1] = x1; pu.u[2] = y0; pu.u[3] = y1;
        pa[kx] = pu.s;
      }

      // P·V as mfma(vf, pa): A rows = d (full 256), B cols = s, k = this t-half
      __builtin_amdgcn_s_setprio(1);
      #pragma unroll
      for (int kx = 0; kx < 2; ++kx) {
        const int c8 = th * 4 + kx * 2 + half; // global 8-t chunk index within tile
        #pragma unroll
        for (int di = 0; di < 8; ++di) {
          int d = di * 32 + l32;
          short8 vf = *(const short8*)(sVc + d * 64 + ((c8 ^ (d & 7)) << 3));
          o[di] = __builtin_amdgcn_mfma_f32_32x32x16_bf16(vf, pa[kx], o[di], 0, 0, 0);
        }
      }
      __builtin_amdgcn_s_setprio(0);
    }

    if (it < 31) __builtin_amdgcn_s_waitcnt(0x0F70);  // vmcnt(0): next tile landed
    sync_lds();                              // single barrier per iter
  }

  // ---- epilogue: o is complete (all t accumulated in-wave) -> direct store ----
  const int s = s0 + w * 32 + l32;
  if (s < SL) {
    float* op = out + (size_t)n * CO * SL + s;
    #pragma unroll
    for (int di = 0; di < 8; ++di)
      #pragma unroll
      for (int r = 0; r < 16; ++r) {
        int d = di * 32 + (r & 3) + 8 * (r >> 2) + 4 * half;
        __builtin_nontemporal_store(o[di][r], op + (size_t)d * SL);
      }
  }
#undef STAGE_TILE
}

extern "C" void kernel_launch(void* const* d_in, const int* in_sizes, int n_in,
                              void* d_out, int out_size, void* d_ws, size_t ws_size,
                              hipStream_t stream) {
  const float* x      = (const float*)d_in[0];
  const float* conv_w = (const float*)d_in[1];
  const float* conv_b = (const float*)d_in[2];
  const float* wq     = (const float*)d_in[3];
  const float* bq     = (const float*)d_in[4];
  const float* wk     = (const float*)d_in[5];
  const float* bk     = (const float*)d_in[6];
  const float* wv     = (const float*)d_in[7];
  const float* bv     = (const float*)d_in[8];

  char* ws = (char*)d_ws;
  unsigned short* xt  = (unsigned short*)(ws + XT_OFF);
  unsigned short* cw  = (unsigned short*)(ws + CW_OFF);
  unsigned short* wqb = (unsigned short*)(ws + WQ_OFF);
  unsigned short* wkb = (unsigned short*)(ws + WK_OFF);
  unsigned short* wvb = (unsigned short*)(ws + WV_OFF);
  unsigned short* hb  = (unsigned short*)(ws + H_OFF);
  unsigned short* qb  = (unsigned short*)(ws + Q_OFF);
  unsigned short* kb  = (unsigned short*)(ws + K_OFF);
  unsigned short* vtb = (unsigned short*)(ws + VT_OFF);

  hipLaunchKernelGGL(xpose_kernel, dim3(64, 4, 16), dim3(32, 8), 0, stream, x, xt);
  hipLaunchKernelGGL(wconv_kernel, dim3(1024), dim3(256), 0, stream, conv_w, cw);
  hipLaunchKernelGGL(wqkv_kernel,  dim3(192), dim3(256), 0, stream,
                     wq, wk, wv, wqb, wkb, wvb);
  hipLaunchKernelGGL(conv_gemm, dim3(16, 16, 2), dim3(256), 0, stream, xt, cw, conv_b, hb);
  hipLaunchKernelGGL(lin_gemm,  dim3(256, 2, 3), dim3(256), 0, stream,
                     hb, wqb, wkb, wvb, bq, bk, bv, qb, kb, vtb);
  hipLaunchKernelGGL(attn_kernel, dim3(256), dim3(256), 0, stream,
                     qb, kb, vtb, (float*)d_out);
}